// Round 18
// baseline (506.632 us; speedup 1.0000x reference)
//
#include <hip/hip_runtime.h>

// 3D reaction-diffusion tumor solver, 160^3 f32 grid, 30 explicit Euler steps.
// R21: TEMPORAL 2-STEP FUSION re-blocked to 256-thread blocks (residency fix).
//
// R19/R20 post-mortem (both deadlocked): measured occupancy model (waves/CU
// halves at VGPR={64,128,256} -> 32/16/8) + launch_bounds(320,5)'s 102-VGPR
// cap -> 16 waves/CU -> floor(16/5)=3 blocks/CU = 768 < 800 resident ->
// forward-dep spin deadlock. LDS was never the binding constraint. Fix:
// 256-thread blocks (4 waves) — launch_bounds(256,4) caps VGPR at 128,
// giving 16 waves/CU worst-case -> 4 blocks/CU -> 1024 >= 800 by
// construction under BOTH official and measured models (the R12-R18 proven
// shape). LDS cut to [6][10][160]=38,400B (x-halo cols deleted; block spans
// full x so x-halos are grid-boundary zeros -> 2 selects in phase 2);
// 4 x 38,912 (1KiB granule) = 155,648 <= 163,840 pool, ~8KB slack.
//
// Structure per macro-round (2 physics steps): phase1 computes t+1 on the
// halo-1 region (6z x 10y x 160x, 2400 groups, 10 strided iters) from
// global -> LDS; phase2 computes t+2 for own cells (1280 groups, exactly
// 5/thread) from LDS -> global ping-pong (last round -> out). ONE flag hop
// + ONE grid write per TWO steps. Deps = 8 (dz,dy) neighbors via monotone
// relaxed agent flags (replay-safe; ping-pong WAR safe by two-sided skew).
// sc0 own-XCD L2 / sc1 cross-XCD from prologue-computed producer bitmask
// (50 bits); store classes cover depth-2 readers. No agent fences in loop;
// API-free plain launch.

#define NX 160
#define NY 160
#define NZ 160
#define NXQ (NX / 4)              // 40 float4 groups per row
#define NPLANE (NX * NY)          // 25600 floats per z-plane

#define CT_BS 256
#define NYT 20                    // y-tiles (160/8)
#define NZQ 40                    // z-quads (160/4)
#define CT_NBLOCKS (NYT * NZQ)    // 800; lb = zq*20 + yt

typedef float f32x4 __attribute__((ext_vector_type(4)));

// ---- sync state (zero-init at module load; monotone) ----
__device__ unsigned int g_flag[CT_NBLOCKS * 16];   // done flags, 64B-strided
__device__ unsigned int g_xcdmap[CT_NBLOCKS];      // per-block physical XCC id

// Scoped-load/store asm (flg = "" / " sc0" / " sc1").
#define GLD4(dst, voff, base, flg) \
    asm volatile("global_load_dwordx4 %0, %1, %2" flg \
                 : "=v"(dst) : "v"(voff), "s"(base))
#define GLD1(dst, voff, base, flg) \
    asm volatile("global_load_dword %0, %1, %2" flg \
                 : "=v"(dst) : "v"(voff), "s"(base))
#define GST4(voff, val, base, flg) \
    asm volatile("global_store_dwordx4 %0, %1, %2" flg \
                 :: "v"(voff), "v"(val), "s"(base) : "memory")

__device__ __forceinline__ f32x4 ld4v(const float* p) {
    return *reinterpret_cast<const f32x4*>(p);
}

// One Euler step for a float4 column (identical FP order to all prior rounds).
__device__ __forceinline__ f32x4 step_cell(
    f32x4 cc, f32x4 ym, f32x4 yp, f32x4 zm, f32x4 zp,
    float xl, float xr, f32x4 tm, float D, float rho, float delta_t)
{
    f32x4 o;
    float lap, g;
    lap = xl    + cc[1] + ym[0] + yp[0] + zm[0] + zp[0] - 6.f * cc[0];
    g   = D * lap + rho * cc[0] * (1.f - cc[0]) - 2.f * tm[0] * cc[0];
    o[0] = fminf(fmaxf(cc[0] + g * delta_t, 0.f), 1.f);
    lap = cc[0] + cc[2] + ym[1] + yp[1] + zm[1] + zp[1] - 6.f * cc[1];
    g   = D * lap + rho * cc[1] * (1.f - cc[1]) - 2.f * tm[1] * cc[1];
    o[1] = fminf(fmaxf(cc[1] + g * delta_t, 0.f), 1.f);
    lap = cc[1] + cc[3] + ym[2] + yp[2] + zm[2] + zp[2] - 6.f * cc[2];
    g   = D * lap + rho * cc[2] * (1.f - cc[2]) - 2.f * tm[2] * cc[2];
    o[2] = fminf(fmaxf(cc[2] + g * delta_t, 0.f), 1.f);
    lap = cc[2] + xr    + ym[3] + yp[3] + zm[3] + zp[3] - 6.f * cc[3];
    g   = D * lap + rho * cc[3] * (1.f - cc[3]) - 2.f * tm[3] * cc[3];
    o[3] = fminf(fmaxf(cc[3] + g * delta_t, 0.f), 1.f);
    return o;
}

// Scoped masked stencil step from global for one float4 group at (gz,gy,hx).
__device__ __forceinline__ f32x4 step_halo(
    const float* rd, const float* ther, int gz, int gy, int hx,
    bool cC, bool cYm, bool cYp, bool cZm, bool cZp,
    float D, float rho, float delta_t)
{
    const int bb  = (gz * NY + gy) * NX + 4 * hx;
    const int iym = bb + ((gy > 0)       ? -NX : 0);
    const int iyp = bb + ((gy < NY - 1)  ?  NX : 0);
    const int izm = bb + ((gz > 0)       ? -NPLANE : 0);
    const int izp = bb + ((gz < NZ - 1)  ?  NPLANE : 0);
    const int ixl = bb + ((hx > 0)       ? -1 : 0);
    const int ixr = bb + ((hx < NXQ - 1) ?  4 : 3);
    f32x4 cc, ym, yp, zm, zp;
    float xl, xr;
    if (cC)  { GLD4(cc, (unsigned)bb  * 4u, rd, " sc1"); }
    else     { GLD4(cc, (unsigned)bb  * 4u, rd, " sc0"); }
    if (cYm) { GLD4(ym, (unsigned)iym * 4u, rd, " sc1"); }
    else     { GLD4(ym, (unsigned)iym * 4u, rd, " sc0"); }
    if (cYp) { GLD4(yp, (unsigned)iyp * 4u, rd, " sc1"); }
    else     { GLD4(yp, (unsigned)iyp * 4u, rd, " sc0"); }
    if (cZm) { GLD4(zm, (unsigned)izm * 4u, rd, " sc1"); }
    else     { GLD4(zm, (unsigned)izm * 4u, rd, " sc0"); }
    if (cZp) { GLD4(zp, (unsigned)izp * 4u, rd, " sc1"); }
    else     { GLD4(zp, (unsigned)izp * 4u, rd, " sc0"); }
    if (cC)  { GLD1(xl, (unsigned)ixl * 4u, rd, " sc1");
               GLD1(xr, (unsigned)ixr * 4u, rd, " sc1"); }
    else     { GLD1(xl, (unsigned)ixl * 4u, rd, " sc0");
               GLD1(xr, (unsigned)ixr * 4u, rd, " sc0"); }
    const f32x4 tm = ld4v(ther + bb);
    asm volatile("s_waitcnt vmcnt(0)" ::: "memory");
    __builtin_amdgcn_sched_barrier(0);
    const f32x4 z4 = {0.f, 0.f, 0.f, 0.f};
    if (gy == 0)       ym = z4;
    if (gy == NY - 1)  yp = z4;
    if (gz == 0)       zm = z4;
    if (gz == NZ - 1)  zp = z4;
    if (hx == 0)       xl = 0.f;
    if (hx == NXQ - 1) xr = 0.f;
    return step_cell(cc, ym, yp, zm, zp, xl, xr, tm, D, rho, delta_t);
}

#define MAPLD(b) __hip_atomic_load(&g_xcdmap[(b)], __ATOMIC_RELAXED, \
                                   __HIP_MEMORY_SCOPE_AGENT)

// ---------------- fused 2-step scoped-coherence kernel ----------------
__global__ __launch_bounds__(CT_BS, 4) void therapy_all(
    const float* __restrict__ c_init,
    const float* __restrict__ ther,
    float* __restrict__ out,
    float* __restrict__ ws,
    const float* __restrict__ Dp,
    const float* __restrict__ rhop,
    const float* __restrict__ dtp,
    const int* __restrict__ stepsp)
{
    __shared__ float lds[6][10][160];   // t+1 scratch, 38,400 B

    // Bijective XCD swizzle (800 % 8 == 0): contiguous lb per XCD.
    const int lb = (blockIdx.x & 7) * (CT_NBLOCKS / 8) + (blockIdx.x >> 3);
    const int tx = threadIdx.x;
    const int zq = lb / NYT, yt = lb % NYT;

    const int   steps   = *stepsp;
    const float D       = *Dp;
    const float rho     = *rhop;
    const float delta_t = *dtp / (float)steps;

    const unsigned int fbase =
        __hip_atomic_load(&g_flag[lb * 16], __ATOMIC_RELAXED,
                          __HIP_MEMORY_SCOPE_AGENT);

    // Own-cell geometry: 5 groups/thread (1280 = 5*256 exactly).
    int bo[5], po[5], yo[5], ho[5];
    f32x4 tv[5];
#pragma unroll
    for (int l = 0; l < 5; ++l) {
        const int idx = tx + l * CT_BS;
        po[l] = idx / 320;
        const int rg = idx % 320;
        yo[l] = rg / 40;
        ho[l] = rg % 40;
        bo[l] = ((4 * zq + po[l]) * NY + (8 * yt + yo[l])) * NX + 4 * ho[l];
        tv[l] = ld4v(ther + bo[l]);
    }

    // ---- prologue: publish XCC id, 8-dep handshake ----
    unsigned int myx;
    asm volatile("s_getreg_b32 %0, hwreg(HW_REG_XCC_ID)" : "=s"(myx));
    if (tx == 0) {
        __hip_atomic_store(&g_xcdmap[lb], myx, __ATOMIC_RELAXED,
                           __HIP_MEMORY_SCOPE_AGENT);
        asm volatile("s_waitcnt vmcnt(0)" ::: "memory");
        __hip_atomic_store(&g_flag[lb * 16], fbase + 1u, __ATOMIC_RELAXED,
                           __HIP_MEMORY_SCOPE_AGENT);
    }
    if (tx < 8) {
        const int dlt8[8] = {-NYT - 1, -NYT, -NYT + 1, -1, 1,
                              NYT - 1,  NYT,  NYT + 1};
        int nb = lb + dlt8[tx];
        nb = nb < 0 ? 0 : (nb >= CT_NBLOCKS ? CT_NBLOCKS - 1 : nb);
        while (__hip_atomic_load(&g_flag[nb * 16], __ATOMIC_RELAXED,
                                 __HIP_MEMORY_SCOPE_AGENT) < fbase + 1u) {
            __builtin_amdgcn_s_sleep(2);
        }
    }
    __syncthreads();

    // ---- store-side classification (depth-2 readers) ----
    #define CROSSB(d) ({ int nb_ = lb + (d); \
        (nb_ >= 0 && nb_ < CT_NBLOCKS) ? (MAPLD(nb_) != myx) : false; })
    const bool czlo = CROSSB(-NYT) || CROSSB(-NYT - 1) || CROSSB(-NYT + 1);
    const bool czhi = CROSSB( NYT) || CROSSB( NYT - 1) || CROSSB( NYT + 1);
    const bool cylo = CROSSB(-1);
    const bool cyhi = CROSSB(1);
    bool stp[5];
#pragma unroll
    for (int l = 0; l < 5; ++l) {
        const bool stY = (yo[l] <= 1 && cylo) || (yo[l] >= 6 && cyhi);
        stp[l] = stY || (po[l] <= 1 ? czlo : czhi);
    }

    // ---- load-side classification: 5 producers per region group ----
    unsigned long long clsm = 0ull;
#pragma unroll
    for (int l = 0; l < 10; ++l) {
        const int idx = tx + l * CT_BS;
        if (idx < 2400) {
            const int yy = (idx / 40) % 10, zz = idx / 400;
            const int gz = 4 * zq + zz - 1, gy = 8 * yt + yy - 1;
            if (gy >= 0 && gy < NY && gz >= 0 && gz < NZ) {
                const int dzs[5] = {0, 0, 0, -1, 1};
                const int dys[5] = {0, -1, 1, 0, 0};
#pragma unroll
                for (int s = 0; s < 5; ++s) {
                    int Z = gz + dzs[s]; Z = Z < 0 ? 0 : (Z > NZ - 1 ? NZ - 1 : Z);
                    int Y = gy + dys[s]; Y = Y < 0 ? 0 : (Y > NY - 1 ? NY - 1 : Y);
                    const int lbp = (Z >> 2) * NYT + (Y >> 3);
                    if (MAPLD(lbp) != myx) clsm |= (1ull << (5 * l + s));
                }
            }
        }
    }

    const int NM = steps >> 1;
    const int W  = NM + (steps & 1);

    const float* rd = c_init;
    for (int w = 0; w < NM; ++w) {
        float* wr = (((W - 1 - w) & 1) == 0) ? out : ws;

        // RAW+WAR wait: 8 dep blocks finished macro-round w-1.
        if (w > 0 && tx < 8) {
            const int dlt8[8] = {-NYT - 1, -NYT, -NYT + 1, -1, 1,
                                  NYT - 1,  NYT,  NYT + 1};
            int nb = lb + dlt8[tx];
            nb = nb < 0 ? 0 : (nb >= CT_NBLOCKS ? CT_NBLOCKS - 1 : nb);
            const unsigned tgt = fbase + 1u + (unsigned)w;
            while (__hip_atomic_load(&g_flag[nb * 16], __ATOMIC_RELAXED,
                                     __HIP_MEMORY_SCOPE_AGENT) < tgt) {
                __builtin_amdgcn_s_sleep(2);
            }
        }
        __syncthreads();

        // ---- phase 1: t+1 on the 6z x 10y x 160x region -> LDS ----
#pragma unroll
        for (int l = 0; l < 10; ++l) {
            const int idx = tx + l * CT_BS;
            if (idx < 2400) {
                const int h1 = idx % 40, yy = (idx / 40) % 10, zz = idx / 400;
                const int gz = 4 * zq + zz - 1, gy = 8 * yt + yy - 1;
                f32x4 v = {0.f, 0.f, 0.f, 0.f};
                if (gy >= 0 && gy < NY && gz >= 0 && gz < NZ) {
                    v = step_halo(rd, ther, gz, gy, h1,
                                  (clsm >> (5 * l + 0)) & 1,
                                  (clsm >> (5 * l + 1)) & 1,
                                  (clsm >> (5 * l + 2)) & 1,
                                  (clsm >> (5 * l + 3)) & 1,
                                  (clsm >> (5 * l + 4)) & 1,
                                  D, rho, delta_t);
                }
                *reinterpret_cast<f32x4*>(&lds[zz][yy][4 * h1]) = v;
            }
        }
        __syncthreads();

        // ---- phase 2: t+2 for own cells from LDS -> global ----
#pragma unroll
        for (int l = 0; l < 5; ++l) {
            const int zz = po[l] + 1, yy = yo[l] + 1, xc = 4 * ho[l];
            const f32x4 cc = *reinterpret_cast<const f32x4*>(&lds[zz][yy][xc]);
            const f32x4 ym = *reinterpret_cast<const f32x4*>(&lds[zz][yy - 1][xc]);
            const f32x4 yp = *reinterpret_cast<const f32x4*>(&lds[zz][yy + 1][xc]);
            const f32x4 zm = *reinterpret_cast<const f32x4*>(&lds[zz - 1][yy][xc]);
            const f32x4 zp = *reinterpret_cast<const f32x4*>(&lds[zz + 1][yy][xc]);
            // x-halos: block spans full x, so only grid boundary (zero).
            const float xl = (ho[l] == 0)       ? 0.f : lds[zz][yy][xc - 1];
            const float xr = (ho[l] == NXQ - 1) ? 0.f : lds[zz][yy][xc + 4];
            const f32x4 n = step_cell(cc, ym, yp, zm, zp, xl, xr, tv[l],
                                      D, rho, delta_t);
            const unsigned ob = (unsigned)bo[l] * 4u;
            if (stp[l]) { GST4(ob, n, wr, " sc1"); }
            else        { GST4(ob, n, wr, ""); }
        }

        // Drain stores (per-wave vmcnt(0) before s_barrier) + LDS-reuse
        // barrier, then post done.
        __syncthreads();
        if (tx == 0) {
            __hip_atomic_store(&g_flag[lb * 16], fbase + 2u + (unsigned)w,
                               __ATOMIC_RELAXED, __HIP_MEMORY_SCOPE_AGENT);
        }
        rd = wr;
    }

    // ---- odd-steps tail: one single step for own cells -> out ----
    if (steps & 1) {
        if (tx < 8) {
            const int dlt8[8] = {-NYT - 1, -NYT, -NYT + 1, -1, 1,
                                  NYT - 1,  NYT,  NYT + 1};
            int nb = lb + dlt8[tx];
            nb = nb < 0 ? 0 : (nb >= CT_NBLOCKS ? CT_NBLOCKS - 1 : nb);
            const unsigned tgt = fbase + 1u + (unsigned)(W - 1);
            while (__hip_atomic_load(&g_flag[nb * 16], __ATOMIC_RELAXED,
                                     __HIP_MEMORY_SCOPE_AGENT) < tgt) {
                __builtin_amdgcn_s_sleep(2);
            }
        }
        __syncthreads();
#pragma unroll
        for (int l = 0; l < 5; ++l) {
            const int gz = 4 * zq + po[l], gy = 8 * yt + yo[l];
            const f32x4 n = step_halo(rd, ther, gz, gy, ho[l],
                                      true, true, true, true, true,
                                      D, rho, delta_t);
            GST4((unsigned)bo[l] * 4u, n, out, "");
        }
        __syncthreads();
        if (tx == 0) {
            __hip_atomic_store(&g_flag[lb * 16], fbase + 2u + (unsigned)(W - 1),
                               __ATOMIC_RELAXED, __HIP_MEMORY_SCOPE_AGENT);
        }
    }
}

extern "C" void kernel_launch(void* const* d_in, const int* in_sizes, int n_in,
                              void* d_out, int out_size, void* d_ws, size_t ws_size,
                              hipStream_t stream) {
    const float* c_init = (const float*)d_in[0];
    const float* Dp     = (const float*)d_in[1];
    const float* rhop   = (const float*)d_in[2];
    const float* dtp    = (const float*)d_in[3];
    const float* ther   = (const float*)d_in[4];
    const int*   stepsp = (const int*)d_in[5];

    float* out = (float*)d_out;
    float* wsA = (float*)d_ws;   // ping-pong grid buffer (16.4 MB)

    // NO runtime API calls (graph-capture-safe). Co-residency by
    // construction: launch_bounds(256,4) caps VGPR at 128 -> >=16 waves/CU
    // under the measured occupancy model -> 4 blocks/CU x 4 waves; LDS
    // 38,400B -> 4 x 38,912 (1KiB granule) = 155,648 <= 163,840 pool.
    // => 1024 co-resident blocks >= 800 launched.
    therapy_all<<<dim3(CT_NBLOCKS), dim3(CT_BS), 0, stream>>>(
        c_init, ther, out, wsA, Dp, rhop, dtp, stepsp);
}

// Round 19
// 238.728 us; speedup vs baseline: 2.1222x; 2.1222x over previous
//
#include <hip/hip_runtime.h>

// 3D reaction-diffusion tumor solver, 160^3 f32 grid, 30 explicit Euler steps.
// R22 = R17 resubmitted (best verified: timed 234.3us, device 162us).
//
// R21 post-mortem: 2-step fusion ran correctly (residency fixed by 256-thr
// blocks) but FETCH exploded 110->663MB/dispatch (halo-recompute reads each
// cell ~7x and overlapping neighbor regions miss local L2) -> 506us. Fusion
// only pays when sync >> traffic; scoped coherence already made sync ~2.5us.
// R17 is the local optimum of the {hops x traffic} trade: 1 flag hop/step +
// ping-pong. Banking it.
//
// R17: scoped-coherence persistent kernel, GPT=4, double buffer (ping-pong).
// 1000 blocks x 256 thr, z-quads (internal z-faces from registers), deps
// {-25,-1,+1,+25} via monotone relaxed agent flags (replay-safe), runtime
// XCC-id link classification (sc0 own-XCD L2 / sc1 cross-XCD via IC), no
// agent fences in the loop (no L2 flush/invalidate), ping-pong WAR-safe by
// two-sided skew bound, API-free plain launch (graph-capture-safe;
// co-residency compile-time guaranteed: launch_bounds(256,4) -> >=1024
// co-resident >= 1000 launched).

#define NX 160
#define NY 160
#define NZ 160
#define NXQ (NX / 4)              // 40 float4 groups per row
#define NPLANE (NX * NY)          // 25600 floats per z-plane
#define NGROUPS (NZ * NY * NXQ)   // 1,024,000 float4 groups

// --- persistent config: 256-thread blocks, z-quads ---
#define CT_BS 256
#define CT_NTHREADS (NGROUPS / 4)        // 256,000 (4 planes each)
#define CT_NBLOCKS (CT_NTHREADS / CT_BS) // 1000
#define BPQ 25                           // blocks per z-quad slab (6400/256)

typedef float f32x4 __attribute__((ext_vector_type(4)));

// ---- sync state (zero-init at module load) ----
__device__ unsigned int g_flag[CT_NBLOCKS * 16];   // one flag per 64B line
__device__ unsigned int g_xcdmap[CT_NBLOCKS];      // per-block physical XCC id

// Scoped-load/store asm (flg = "" / " sc0" / " sc1").
#define GLD4(dst, voff, base, flg) \
    asm volatile("global_load_dwordx4 %0, %1, %2" flg \
                 : "=v"(dst) : "v"(voff), "s"(base))
#define GLD1(dst, voff, base, flg) \
    asm volatile("global_load_dword %0, %1, %2" flg \
                 : "=v"(dst) : "v"(voff), "s"(base))
#define GST4(voff, val, base, flg) \
    asm volatile("global_store_dwordx4 %0, %1, %2" flg \
                 :: "v"(voff), "v"(val), "s"(base) : "memory")

__device__ __forceinline__ f32x4 ld4v(const float* p) {
    return *reinterpret_cast<const f32x4*>(p);
}

// One Euler step for a float4 column (identical FP order to all prior rounds).
__device__ __forceinline__ f32x4 step_cell(
    f32x4 cc, f32x4 ym, f32x4 yp, f32x4 zm, f32x4 zp,
    float xl, float xr, f32x4 tm, float D, float rho, float delta_t)
{
    f32x4 o;
    float lap, g;
    lap = xl    + cc[1] + ym[0] + yp[0] + zm[0] + zp[0] - 6.f * cc[0];
    g   = D * lap + rho * cc[0] * (1.f - cc[0]) - 2.f * tm[0] * cc[0];
    o[0] = fminf(fmaxf(cc[0] + g * delta_t, 0.f), 1.f);
    lap = cc[0] + cc[2] + ym[1] + yp[1] + zm[1] + zp[1] - 6.f * cc[1];
    g   = D * lap + rho * cc[1] * (1.f - cc[1]) - 2.f * tm[1] * cc[1];
    o[1] = fminf(fmaxf(cc[1] + g * delta_t, 0.f), 1.f);
    lap = cc[1] + cc[3] + ym[2] + yp[2] + zm[2] + zp[2] - 6.f * cc[2];
    g   = D * lap + rho * cc[2] * (1.f - cc[2]) - 2.f * tm[2] * cc[2];
    o[2] = fminf(fmaxf(cc[2] + g * delta_t, 0.f), 1.f);
    lap = cc[2] + xr    + ym[3] + yp[3] + zm[3] + zp[3] - 6.f * cc[3];
    g   = D * lap + rho * cc[3] * (1.f - cc[3]) - 2.f * tm[3] * cc[3];
    o[3] = fminf(fmaxf(cc[3] + g * delta_t, 0.f), 1.f);
    return o;
}

// ---------------- scoped-coherence all-steps kernel ----------------
__global__ __launch_bounds__(CT_BS, 4) void therapy_all(
    const float* __restrict__ c_init,
    const float* __restrict__ ther,
    float* __restrict__ out,
    float* __restrict__ ws,
    const float* __restrict__ Dp,
    const float* __restrict__ rhop,
    const float* __restrict__ dtp,
    const int* __restrict__ stepsp)
{
    __shared__ float2 lx[4][CT_BS];   // per-plane {x0 (reader's xr), x3 (xl)}

    // Bijective XCD swizzle (1000 % 8 == 0): each XCD owns 125 contiguous
    // logical blocks = 5 whole z-quad slabs (locality only; correctness
    // comes from the runtime link classification below).
    const int lb = (blockIdx.x & 7) * (CT_NBLOCKS / 8) + (blockIdx.x >> 3);
    const int tx = threadIdx.x;
    const int tid = lb * CT_BS + tx;

    const int xq = tid % NXQ;           // 0..39
    const int t2 = tid / NXQ;
    const int y  = t2 % NY;             // 0..159
    const int q  = lb / BPQ;            // z-quad index, block-uniform (0..39)

    const int   steps   = *stepsp;
    const float D       = *Dp;
    const float rho     = *rhop;
    const float delta_t = *dtp / (float)steps;

    const unsigned int fbase =
        __hip_atomic_load(&g_flag[lb * 16], __ATOMIC_RELAXED,
                          __HIP_MEMORY_SCOPE_AGENT);

    const int  offym = (y > 0)        ? -NX : 0;
    const int  offyp = (y < NY - 1)   ?  NX : 0;
    const int  offxl = (xq > 0)       ? -1  : 0;
    const bool mym = (y == 0), myp = (y == NY - 1);
    const bool mxl = (xq == 0), mxr = (xq == NXQ - 1);
    const bool mzm = (q == 0);
    const bool mzp = (q == 39);

    const int b0 = ((4 * q) * NY + y) * NX + 4 * xq;   // plane 4q (floats)
    const int b3 = b0 + 3 * NPLANE;                    // plane 4q+3

    const unsigned o_c  = (unsigned)b0 * 4u;
    const unsigned o_ym = (unsigned)(b0 + offym) * 4u;
    const unsigned o_yp = (unsigned)(b0 + offyp) * 4u;
    const unsigned o_xl = (unsigned)(b0 + offxl) * 4u;
    const unsigned o_xr = (unsigned)(b0 + (mxr ? 3 : 4)) * 4u;
    const unsigned o_zm = (unsigned)(b0 + (mzm ? 0 : -NPLANE)) * 4u;
    const unsigned o_zp = (unsigned)(b3 + (mzp ? 0 :  NPLANE)) * 4u;

    f32x4 tv[4], cv[4];
#pragma unroll
    for (int p = 0; p < 4; ++p) {
        tv[p] = ld4v(ther   + b0 + p * NPLANE);
        cv[p] = ld4v(c_init + b0 + p * NPLANE);
    }

    // ---- prologue: publish physical XCC id, handshake, classify links ----
    unsigned int myx;
    asm volatile("s_getreg_b32 %0, hwreg(HW_REG_XCC_ID)" : "=s"(myx));
    if (tx == 0) {
        __hip_atomic_store(&g_xcdmap[lb], myx, __ATOMIC_RELAXED,
                           __HIP_MEMORY_SCOPE_AGENT);
        asm volatile("s_waitcnt vmcnt(0)" ::: "memory");
        __hip_atomic_store(&g_flag[lb * 16], fbase + 1u, __ATOMIC_RELAXED,
                           __HIP_MEMORY_SCOPE_AGENT);
    }
    if (tx < 4) {
        const int d = (tx == 0) ? -BPQ : (tx == 1) ? -1 : (tx == 2) ? 1 : BPQ;
        int nb = lb + d;
        nb = nb < 0 ? 0 : (nb >= CT_NBLOCKS ? CT_NBLOCKS - 1 : nb);
        while (__hip_atomic_load(&g_flag[nb * 16], __ATOMIC_RELAXED,
                                 __HIP_MEMORY_SCOPE_AGENT) < fbase + 1u) {
            __builtin_amdgcn_s_sleep(2);
        }
    }
    __syncthreads();

    #define MAPLD(b) __hip_atomic_load(&g_xcdmap[(b)], __ATOMIC_RELAXED, \
                                       __HIP_MEMORY_SCOPE_AGENT)
    const unsigned xm25 = (lb >= BPQ)              ? MAPLD(lb - BPQ) : myx;
    const unsigned xm1  = (lb >= 1)                ? MAPLD(lb - 1)   : myx;
    const unsigned xp1  = (lb < CT_NBLOCKS - 1)    ? MAPLD(lb + 1)   : myx;
    const unsigned xp25 = (lb < CT_NBLOCKS - BPQ)  ? MAPLD(lb + BPQ) : myx;

    const bool zmX = (xm25 != myx);
    const bool zpX = (xp25 != myx);
    const bool ymX = (tx < NXQ)          && (xm1 != myx);
    const bool ypX = (tx >= CT_BS - NXQ) && (xp1 != myx);
    const bool xlX = (tx == 0)           && (xm1 != myx);
    const bool xrX = (tx == CT_BS - 1)   && (xp1 != myx);
    const bool stYX = (tx < NXQ && xm1 != myx) ||
                      (tx >= CT_BS - NXQ && xp1 != myx);
    const bool st0X = stYX || zmX;
    const bool st3X = stYX || zpX;

    const float* rd = c_init;
    for (int i = 0; i < steps; ++i) {
        // Ping-pong: align so step steps-1 lands in out.
        float* wr = (((steps - 1 - i) & 1) == 0) ? out : ws;

        // A: publish x-exchange values (previous-step cv == rd values)
#pragma unroll
        for (int p = 0; p < 4; ++p)
            lx[p][tx] = make_float2(cv[p][0], cv[p][3]);

        // B: wait for the 4 dependency blocks to have finished step i-1
        //    (RAW: their step i-1 outputs; WAR: they are done reading the
        //     buffer this step overwrites — ping-pong safety)
        if (i > 0 && tx < 4) {
            const int d = (tx == 0) ? -BPQ : (tx == 1) ? -1
                        : (tx == 2) ?    1 : BPQ;
            int nb = lb + d;
            nb = nb < 0 ? 0 : (nb >= CT_NBLOCKS ? CT_NBLOCKS - 1 : nb);
            const unsigned tgt = fbase + 1u + (unsigned)i;
            while (__hip_atomic_load(&g_flag[nb * 16], __ATOMIC_RELAXED,
                                     __HIP_MEMORY_SCOPE_AGENT) < tgt) {
                __builtin_amdgcn_s_sleep(2);
            }
        }
        __syncthreads();

        // C: neighbor loads (sc0 = own-XCD L2; sc1 = cross-XCD via IC)
        f32x4 ym[4], yp[4], zmg, zpg;
#pragma unroll
        for (int p = 0; p < 4; ++p) {
            const unsigned po = (unsigned)(p * NPLANE * 4);
            if (ymX) { GLD4(ym[p], o_ym + po, rd, " sc1"); }
            else     { GLD4(ym[p], o_ym + po, rd, " sc0"); }
            if (ypX) { GLD4(yp[p], o_yp + po, rd, " sc1"); }
            else     { GLD4(yp[p], o_yp + po, rd, " sc0"); }
        }
        if (zmX) { GLD4(zmg, o_zm, rd, " sc1"); } else { GLD4(zmg, o_zm, rd, " sc0"); }
        if (zpX) { GLD4(zpg, o_zp, rd, " sc1"); } else { GLD4(zpg, o_zp, rd, " sc0"); }
        float xl[4], xr[4];
        if (tx == 0) {
#pragma unroll
            for (int p = 0; p < 4; ++p) {
                const unsigned po = (unsigned)(p * NPLANE * 4);
                if (xlX) { GLD1(xl[p], o_xl + po, rd, " sc1"); }
                else     { GLD1(xl[p], o_xl + po, rd, " sc0"); }
            }
        } else {
#pragma unroll
            for (int p = 0; p < 4; ++p) xl[p] = lx[p][tx - 1].y;
        }
        if (tx == CT_BS - 1) {
#pragma unroll
            for (int p = 0; p < 4; ++p) {
                const unsigned po = (unsigned)(p * NPLANE * 4);
                if (xrX) { GLD1(xr[p], o_xr + po, rd, " sc1"); }
                else     { GLD1(xr[p], o_xr + po, rd, " sc0"); }
            }
        } else {
#pragma unroll
            for (int p = 0; p < 4; ++p) xr[p] = lx[p][tx + 1].x;
        }
        asm volatile("s_waitcnt vmcnt(0)" ::: "memory");
        __builtin_amdgcn_sched_barrier(0);

        // D: boundary masks + compute (internal z-faces from registers)
        const f32x4 z4 = {0.f, 0.f, 0.f, 0.f};
        if (mym) {
#pragma unroll
            for (int p = 0; p < 4; ++p) ym[p] = z4;
        }
        if (myp) {
#pragma unroll
            for (int p = 0; p < 4; ++p) yp[p] = z4;
        }
        if (mzm) zmg = z4;
        if (mzp) zpg = z4;
        if (mxl) {
#pragma unroll
            for (int p = 0; p < 4; ++p) xl[p] = 0.f;
        }
        if (mxr) {
#pragma unroll
            for (int p = 0; p < 4; ++p) xr[p] = 0.f;
        }

        f32x4 n[4];
        n[0] = step_cell(cv[0], ym[0], yp[0], zmg,   cv[1], xl[0], xr[0], tv[0], D, rho, delta_t);
        n[1] = step_cell(cv[1], ym[1], yp[1], cv[0], cv[2], xl[1], xr[1], tv[1], D, rho, delta_t);
        n[2] = step_cell(cv[2], ym[2], yp[2], cv[1], cv[3], xl[2], xr[2], tv[2], D, rho, delta_t);
        n[3] = step_cell(cv[3], ym[3], yp[3], cv[2], zpg,   xl[3], xr[3], tv[3], D, rho, delta_t);

        // E: stores (interior stay dirty in local L2; cross-read cells sc1)
        if (st0X) { GST4(o_c, n[0], wr, " sc1"); } else { GST4(o_c, n[0], wr, ""); }
        if (stYX) { GST4(o_c + 102400u, n[1], wr, " sc1"); }
        else      { GST4(o_c + 102400u, n[1], wr, ""); }
        if (stYX) { GST4(o_c + 204800u, n[2], wr, " sc1"); }
        else      { GST4(o_c + 204800u, n[2], wr, ""); }
        if (st3X) { GST4(o_c + 307200u, n[3], wr, " sc1"); }
        else      { GST4(o_c + 307200u, n[3], wr, ""); }

        // F: drain stores (syncthreads emits per-wave vmcnt(0) before
        //    s_barrier) then post progress with a relaxed agent store.
        __syncthreads();
        if (tx == 0) {
            __hip_atomic_store(&g_flag[lb * 16], fbase + 2u + (unsigned)i,
                               __ATOMIC_RELAXED, __HIP_MEMORY_SCOPE_AGENT);
        }

#pragma unroll
        for (int p = 0; p < 4; ++p) cv[p] = n[p];
        rd = wr;
    }
}

extern "C" void kernel_launch(void* const* d_in, const int* in_sizes, int n_in,
                              void* d_out, int out_size, void* d_ws, size_t ws_size,
                              hipStream_t stream) {
    const float* c_init = (const float*)d_in[0];
    const float* Dp     = (const float*)d_in[1];
    const float* rhop   = (const float*)d_in[2];
    const float* dtp    = (const float*)d_in[3];
    const float* ther   = (const float*)d_in[4];
    const int*   stepsp = (const int*)d_in[5];

    float* out = (float*)d_out;
    float* wsA = (float*)d_ws;   // ping-pong grid buffer (16.4 MB)

    // NO runtime API calls here (graph-capture-safe). Co-residency is
    // compile-time guaranteed by __launch_bounds__(256,4): >=1024 blocks
    // co-resident >= 1000 launched.
    therapy_all<<<dim3(CT_NBLOCKS), dim3(CT_BS), 0, stream>>>(
        c_init, ther, out, wsA, Dp, rhop, dtp, stepsp);
}